// Round 1
// baseline (2148.621 us; speedup 1.0000x reference)
//
#include <hip/hip_runtime.h>

#define SEQ   1024
#define HID   512
#define NHEAD 8
#define DH    256
#define INTER 2048
#define BATCH 8
#define ROWS  (BATCH * SEQ)   // 8192

#define BM 128
#define BN 128
#define BK 16

// ---------------- embedding + layernorm ----------------
__global__ __launch_bounds__(256) void embed_ln_kernel(
    const int* __restrict__ x, const float* __restrict__ wemb,
    const float* __restrict__ pemb, const float* __restrict__ temb,
    const float* __restrict__ lnw, const float* __restrict__ lnb,
    float* __restrict__ out) {
  int row = blockIdx.x;             // b*SEQ + s
  int s = row & (SEQ - 1);
  int tok = x[row];
  const float* we = wemb + (size_t)tok * HID;
  const float* pe = pemb + (size_t)s * HID;
  int c = threadIdx.x;              // 256 threads, 2 cols each
  float e0 = we[c] + pe[c] + temb[c];
  float e1 = we[c + 256] + pe[c + 256] + temb[c + 256];
  float s1 = e0 + e1, s2 = e0 * e0 + e1 * e1;
  #pragma unroll
  for (int off = 32; off > 0; off >>= 1) {
    s1 += __shfl_down(s1, off, 64);
    s2 += __shfl_down(s2, off, 64);
  }
  __shared__ float r1[4], r2[4];
  int wid = threadIdx.x >> 6, lane = threadIdx.x & 63;
  if (lane == 0) { r1[wid] = s1; r2[wid] = s2; }
  __syncthreads();
  float S1 = r1[0] + r1[1] + r1[2] + r1[3];
  float S2 = r2[0] + r2[1] + r2[2] + r2[3];
  float m = S1 * (1.0f / HID);
  float v = S2 * (1.0f / HID) - m * m;
  float inv = rsqrtf(v + 1e-12f);
  float* o = out + (size_t)row * HID;
  o[c]       = (e0 - m) * inv * lnw[c]       + lnb[c];
  o[c + 256] = (e1 - m) * inv * lnw[c + 256] + lnb[c + 256];
}

// ---------------- C[i,j] = sum_k A[i,k]*B[j,k] (+bias[j]) ----------------
// A: MxK row-major, B: NxK row-major (i.e. C = A @ B^T). M%128==0, N%128==0, K%16==0.
__global__ __launch_bounds__(256) void gemm_bt_kernel(
    const float* __restrict__ A, const float* __restrict__ B,
    float* __restrict__ C, const float* __restrict__ bias,
    int M, int N, int K) {
  __shared__ float As[BK][BM + 4];  // [k][i], +4 keeps 16B alignment
  __shared__ float Bs[BK][BN + 4];  // [k][j]
  int tid = threadIdx.x;
  int tx = tid & 15, ty = tid >> 4;
  int row0 = blockIdx.y * BM, col0 = blockIdx.x * BN;
  int lrow = tid >> 1;              // 0..127
  int lk = (tid & 1) * 8;           // 0 or 8
  const float* Ap = A + (size_t)(row0 + lrow) * K + lk;
  const float* Bp = B + (size_t)(col0 + lrow) * K + lk;
  float acc[8][8] = {};
  for (int k0 = 0; k0 < K; k0 += BK) {
    float4 a0 = *(const float4*)(Ap + k0);
    float4 a1 = *(const float4*)(Ap + k0 + 4);
    float4 b0 = *(const float4*)(Bp + k0);
    float4 b1 = *(const float4*)(Bp + k0 + 4);
    __syncthreads();
    As[lk + 0][lrow] = a0.x; As[lk + 1][lrow] = a0.y;
    As[lk + 2][lrow] = a0.z; As[lk + 3][lrow] = a0.w;
    As[lk + 4][lrow] = a1.x; As[lk + 5][lrow] = a1.y;
    As[lk + 6][lrow] = a1.z; As[lk + 7][lrow] = a1.w;
    Bs[lk + 0][lrow] = b0.x; Bs[lk + 1][lrow] = b0.y;
    Bs[lk + 2][lrow] = b0.z; Bs[lk + 3][lrow] = b0.w;
    Bs[lk + 4][lrow] = b1.x; Bs[lk + 5][lrow] = b1.y;
    Bs[lk + 6][lrow] = b1.z; Bs[lk + 7][lrow] = b1.w;
    __syncthreads();
    #pragma unroll
    for (int k = 0; k < BK; ++k) {
      float4 av0 = *(const float4*)&As[k][ty * 8];
      float4 av1 = *(const float4*)&As[k][ty * 8 + 4];
      float4 bv0 = *(const float4*)&Bs[k][tx * 8];
      float4 bv1 = *(const float4*)&Bs[k][tx * 8 + 4];
      float ar[8] = {av0.x, av0.y, av0.z, av0.w, av1.x, av1.y, av1.z, av1.w};
      float br[8] = {bv0.x, bv0.y, bv0.z, bv0.w, bv1.x, bv1.y, bv1.z, bv1.w};
      #pragma unroll
      for (int i = 0; i < 8; ++i)
        #pragma unroll
        for (int j = 0; j < 8; ++j)
          acc[i][j] += ar[i] * br[j];
    }
  }
  #pragma unroll
  for (int i = 0; i < 8; ++i) {
    int r = row0 + ty * 8 + i;
    float* Cp = C + (size_t)r * N + col0 + tx * 8;
    float o[8];
    #pragma unroll
    for (int j = 0; j < 8; ++j) o[j] = acc[i][j];
    if (bias) {
      #pragma unroll
      for (int j = 0; j < 8; ++j) o[j] += bias[col0 + tx * 8 + j];
    }
    *(float4*)Cp       = make_float4(o[0], o[1], o[2], o[3]);
    *(float4*)(Cp + 4) = make_float4(o[4], o[5], o[6], o[7]);
  }
}

// ---------------- per-head sequence mix + bias + square ----------------
// Y[b,t,h*DH+d] = ( sum_s M[h,s,t] * X[b,s,h*DH+d] + bias[h*DH+d] )^2
__global__ __launch_bounds__(256) void mut_sq_kernel(
    const float* __restrict__ X, const float* __restrict__ Mm,
    const float* __restrict__ bias, float* __restrict__ Y) {
  __shared__ float As[BK][BM + 4];  // [s][t]
  __shared__ float Bs[BK][BN + 4];  // [s][d]
  int tid = threadIdx.x;
  int tx = tid & 15, ty = tid >> 4;
  int b = blockIdx.z >> 3, h = blockIdx.z & 7;
  int t0 = blockIdx.y * BM;
  int d0 = blockIdx.x * BN;
  int lr = tid >> 4;                // s-row within tile: 0..15
  int lc = (tid & 15) * 8;          // col: 0..120
  const float* Mp = Mm + ((size_t)h * SEQ) * SEQ + (size_t)lr * SEQ + t0 + lc;
  const float* Xp = X + ((size_t)(b * SEQ + lr)) * INTER + h * DH + d0 + lc;
  float acc[8][8] = {};
  for (int s0 = 0; s0 < SEQ; s0 += BK) {
    float4 a0 = *(const float4*)(Mp + (size_t)s0 * SEQ);
    float4 a1 = *(const float4*)(Mp + (size_t)s0 * SEQ + 4);
    float4 b0 = *(const float4*)(Xp + (size_t)s0 * INTER);
    float4 b1 = *(const float4*)(Xp + (size_t)s0 * INTER + 4);
    __syncthreads();
    *(float4*)&As[lr][lc]     = a0;
    *(float4*)&As[lr][lc + 4] = a1;
    *(float4*)&Bs[lr][lc]     = b0;
    *(float4*)&Bs[lr][lc + 4] = b1;
    __syncthreads();
    #pragma unroll
    for (int k = 0; k < BK; ++k) {
      float4 av0 = *(const float4*)&As[k][ty * 8];
      float4 av1 = *(const float4*)&As[k][ty * 8 + 4];
      float4 bv0 = *(const float4*)&Bs[k][tx * 8];
      float4 bv1 = *(const float4*)&Bs[k][tx * 8 + 4];
      float ar[8] = {av0.x, av0.y, av0.z, av0.w, av1.x, av1.y, av1.z, av1.w};
      float br[8] = {bv0.x, bv0.y, bv0.z, bv0.w, bv1.x, bv1.y, bv1.z, bv1.w};
      #pragma unroll
      for (int i = 0; i < 8; ++i)
        #pragma unroll
        for (int j = 0; j < 8; ++j)
          acc[i][j] += ar[i] * br[j];
    }
  }
  int colbase = h * DH + d0 + tx * 8;
  #pragma unroll
  for (int i = 0; i < 8; ++i) {
    int t = t0 + ty * 8 + i;
    float* Yp = Y + ((size_t)(b * SEQ + t)) * INTER + colbase;
    float o[8];
    #pragma unroll
    for (int j = 0; j < 8; ++j) {
      float v = acc[i][j] + bias[colbase + j];
      o[j] = v * v;
    }
    *(float4*)Yp       = make_float4(o[0], o[1], o[2], o[3]);
    *(float4*)(Yp + 4) = make_float4(o[4], o[5], o[6], o[7]);
  }
}

extern "C" void kernel_launch(void* const* d_in, const int* in_sizes, int n_in,
                              void* d_out, int out_size, void* d_ws, size_t ws_size,
                              hipStream_t stream) {
  const int*   x        = (const int*)d_in[0];
  const float* wemb     = (const float*)d_in[1];
  const float* pemb     = (const float*)d_in[2];
  const float* temb     = (const float*)d_in[3];
  const float* lnw      = (const float*)d_in[4];
  const float* lnb      = (const float*)d_in[5];
  const float* init_d   = (const float*)d_in[6];
  const float* init_b   = (const float*)d_in[7];
  const float* init_M   = (const float*)d_in[8];
  const float* inter0_d = (const float*)d_in[9];
  const float* inter0_b = (const float*)d_in[10];
  const float* inter0_M = (const float*)d_in[11];
  const float* final_d  = (const float*)d_in[12];
  const float* final_b  = (const float*)d_in[13];
  float* out = (float*)d_out;

  // workspace layout
  float* X0   = (float*)d_ws;                                    // 8192*512   = 16.8 MB
  float* bufA = (float*)((char*)d_ws + (size_t)ROWS * HID * 4);  // 8192*2048  = 67.1 MB
  float* bufB = (float*)((char*)bufA + (size_t)ROWS * INTER * 4);// 8192*2048  = 67.1 MB

  // 1. embeddings + layernorm -> X0 (8192, 512)
  embed_ln_kernel<<<ROWS, 256, 0, stream>>>(x, wemb, pemb, temb, lnw, lnb, X0);

  // 2. bufA = X0 @ init_d^T   (8192x2048, K=512)
  gemm_bt_kernel<<<dim3(INTER / BN, ROWS / BM), 256, 0, stream>>>(
      X0, init_d, bufA, nullptr, ROWS, INTER, HID);

  // 3. bufB = (mut(bufA, init_M) + init_b)^2
  mut_sq_kernel<<<dim3(DH / BN, SEQ / BM, BATCH * NHEAD), 256, 0, stream>>>(
      bufA, init_M, init_b, bufB);

  // 4. bufA = bufB @ inter0_d^T  (8192x2048, K=2048)
  gemm_bt_kernel<<<dim3(INTER / BN, ROWS / BM), 256, 0, stream>>>(
      bufB, inter0_d, bufA, nullptr, ROWS, INTER, INTER);

  // 5. bufB = (mut(bufA, inter0_M) + inter0_b)^2
  mut_sq_kernel<<<dim3(DH / BN, SEQ / BM, BATCH * NHEAD), 256, 0, stream>>>(
      bufA, inter0_M, inter0_b, bufB);

  // 6. out = bufB @ final_d^T + final_b  (8192x512, K=2048)
  gemm_bt_kernel<<<dim3(HID / BN, ROWS / BM), 256, 0, stream>>>(
      bufB, final_d, out, final_b, ROWS, HID, INTER);
}

// Round 3
// 479.732 us; speedup vs baseline: 4.4788x; 4.4788x over previous
//
#include <hip/hip_runtime.h>

typedef _Float16 f16;
typedef _Float16 f16x4 __attribute__((ext_vector_type(4)));
typedef _Float16 f16x8 __attribute__((ext_vector_type(8)));
typedef float    f32x4 __attribute__((ext_vector_type(4)));

#define SEQ   1024
#define HID   512
#define NHEAD 8
#define DH    256
#define INTER 2048
#define BATCH 8
#define ROWS  (BATCH * SEQ)   // 8192

// ---------------------------------------------------------------------------
// core: C(128x128) += A(128xK) * B^T(128xK), both operands k-fast row-major,
// ld == K. BK=32, synchronous reg->LDS staging (m93 pattern), 16x16x32 f16
// MFMA, 4 waves x (4x4 tiles of 16x16). acc C/D: col=lane&15, row=(lane>>4)*4+r.
// ---------------------------------------------------------------------------
__device__ __forceinline__ void mm_core(const f16* __restrict__ At,
                                        const f16* __restrict__ Bt,
                                        int K, f32x4 (&acc)[4][4]) {
  __shared__ __align__(16) f16 As[128 * 32];
  __shared__ __align__(16) f16 Bs[128 * 32];
  const int tid  = threadIdx.x;
  const int lane = tid & 63, wv = tid >> 6;
  const int wm = (wv >> 1) * 64, wn = (wv & 1) * 64;
  const int lrow  = lane & 15;
  const int kfrag = (lane >> 4) * 8;
  // staging: 512 chunks of 16B per 128x32 tile; chunk c -> row c>>2, k (c&3)*8
  const int c1 = wv * 64 + lane;      // 0..255  (chunk id, first 64 rows)
  const int r1 = c1 >> 2, kq1 = (c1 & 3) * 8;
  const int r2 = r1 + 64;             // second 64 rows
  const int eoff = c1 * 8;            // element offset in LDS for chunk c1
  const f16* Ap1 = At + (size_t)r1 * K + kq1;
  const f16* Ap2 = At + (size_t)r2 * K + kq1;
  const f16* Bp1 = Bt + (size_t)r1 * K + kq1;
  const f16* Bp2 = Bt + (size_t)r2 * K + kq1;
  int4 ra1 = *(const int4*)Ap1;
  int4 ra2 = *(const int4*)Ap2;
  int4 rb1 = *(const int4*)Bp1;
  int4 rb2 = *(const int4*)Bp2;
  for (int k0 = 0; k0 < K; k0 += 32) {
    __syncthreads();   // previous iteration's ds_reads complete
    *(int4*)&As[eoff]        = ra1;
    *(int4*)&As[2048 + eoff] = ra2;
    *(int4*)&Bs[eoff]        = rb1;
    *(int4*)&Bs[2048 + eoff] = rb2;
    __syncthreads();   // LDS tiles ready
    if (k0 + 32 < K) { // prefetch next K-slab; VMEM latency hides under MFMA
      ra1 = *(const int4*)(Ap1 + k0 + 32);
      ra2 = *(const int4*)(Ap2 + k0 + 32);
      rb1 = *(const int4*)(Bp1 + k0 + 32);
      rb2 = *(const int4*)(Bp2 + k0 + 32);
    }
    f16x8 af[4], bf[4];
    #pragma unroll
    for (int t = 0; t < 4; ++t) {
      af[t] = *(const f16x8*)&As[(wm + t * 16 + lrow) * 32 + kfrag];
      bf[t] = *(const f16x8*)&Bs[(wn + t * 16 + lrow) * 32 + kfrag];
    }
    #pragma unroll
    for (int i = 0; i < 4; ++i)
      #pragma unroll
      for (int j = 0; j < 4; ++j)
        acc[i][j] = __builtin_amdgcn_mfma_f32_16x16x32_f16(af[i], bf[j],
                                                           acc[i][j], 0, 0, 0);
  }
}

__device__ __forceinline__ void zero_acc(f32x4 (&acc)[4][4]) {
  f32x4 z = {0.f, 0.f, 0.f, 0.f};
  #pragma unroll
  for (int i = 0; i < 4; ++i)
    #pragma unroll
    for (int j = 0; j < 4; ++j) acc[i][j] = z;
}

// ---------------------------------------------------------------------------
// GEMM writing activation in per-head transposed layout Xt[b,h,d,s] (f16).
// A: [8192][K] f16, W: [2048][K] f16. N fixed = 2048 (8 heads x 256).
// ---------------------------------------------------------------------------
__global__ __launch_bounds__(256) void gemm_t_kernel(
    const f16* __restrict__ A, const f16* __restrict__ W,
    f16* __restrict__ Xt, int K) {
  int row0 = blockIdx.y * 128, col0 = blockIdx.x * 128;
  f32x4 acc[4][4];
  zero_acc(acc);
  mm_core(A + (size_t)row0 * K, W + (size_t)col0 * K, K, acc);
  int tid = threadIdx.x, lane = tid & 63, wv = tid >> 6;
  int wm = (wv >> 1) * 64, wn = (wv & 1) * 64;
  int cn = lane & 15, rbase = (lane >> 4) * 4;
  int b = row0 >> 10, sbase = row0 & 1023;
  #pragma unroll
  for (int mt = 0; mt < 4; ++mt) {
    int s = sbase + wm + mt * 16 + rbase;            // 4 consecutive s
    #pragma unroll
    for (int nt = 0; nt < 4; ++nt) {
      int n = col0 + wn + nt * 16 + cn;
      int h = n >> 8, d = n & 255;
      f16x4 v = {(f16)acc[mt][nt][0], (f16)acc[mt][nt][1],
                 (f16)acc[mt][nt][2], (f16)acc[mt][nt][3]};
      *(f16x4*)&Xt[(((size_t)(b * 8 + h) * 256 + d) << 10) + s] = v;
    }
  }
}

// ---------------------------------------------------------------------------
// per-head seq mix + bias + square:
// Y[(b,t),(h,d)] = ( sum_s Mt[h,t,s] * Xt[b,h,d,s] + bias[h,d] )^2   (f16 out)
// ---------------------------------------------------------------------------
__global__ __launch_bounds__(256) void mut_kernel(
    const f16* __restrict__ Mt, const f16* __restrict__ Xt,
    const float* __restrict__ bias, f16* __restrict__ Y) {
  int b = blockIdx.z >> 3, h = blockIdx.z & 7;
  int t0 = blockIdx.y * 128, d0 = blockIdx.x * 128;
  f32x4 acc[4][4];
  zero_acc(acc);
  const f16* Ap = Mt + ((size_t)h << 20) + ((size_t)t0 << 10);
  const f16* Bp = Xt + (((size_t)(b * 8 + h) * 256 + d0) << 10);
  mm_core(Ap, Bp, SEQ, acc);
  int tid = threadIdx.x, lane = tid & 63, wv = tid >> 6;
  int wm = (wv >> 1) * 64, wn = (wv & 1) * 64;
  int cn = lane & 15, rbase = (lane >> 4) * 4;
  #pragma unroll
  for (int mt = 0; mt < 4; ++mt) {
    int t = t0 + wm + mt * 16 + rbase;
    #pragma unroll
    for (int nt = 0; nt < 4; ++nt) {
      int d = d0 + wn + nt * 16 + cn;
      float bb = bias[(h << 8) + d];
      size_t base = (((size_t)(b << 10) + t) << 11) + (h << 8) + d;
      #pragma unroll
      for (int r = 0; r < 4; ++r) {
        float v = acc[mt][nt][r] + bb;
        Y[base + (size_t)r * INTER] = (f16)(v * v);
      }
    }
  }
}

// ---------------------------------------------------------------------------
// final GEMM: out fp32 = A @ W^T + bias.  A: [8192][K] f16, W: [N][K] f16.
// ---------------------------------------------------------------------------
__global__ __launch_bounds__(256) void gemm_out_kernel(
    const f16* __restrict__ A, const f16* __restrict__ W,
    const float* __restrict__ bias, float* __restrict__ out, int K, int N) {
  int row0 = blockIdx.y * 128, col0 = blockIdx.x * 128;
  f32x4 acc[4][4];
  zero_acc(acc);
  mm_core(A + (size_t)row0 * K, W + (size_t)col0 * K, K, acc);
  int tid = threadIdx.x, lane = tid & 63, wv = tid >> 6;
  int wm = (wv >> 1) * 64, wn = (wv & 1) * 64;
  int cn = lane & 15, rbase = (lane >> 4) * 4;
  #pragma unroll
  for (int mt = 0; mt < 4; ++mt) {
    int r0 = row0 + wm + mt * 16 + rbase;
    #pragma unroll
    for (int nt = 0; nt < 4; ++nt) {
      int col = col0 + wn + nt * 16 + cn;
      float bb = bias[col];
      #pragma unroll
      for (int r = 0; r < 4; ++r)
        out[(size_t)(r0 + r) * N + col] = acc[mt][nt][r] + bb;
    }
  }
}

// ---------------------------------------------------------------------------
// embeddings + layernorm -> f16
// ---------------------------------------------------------------------------
__global__ __launch_bounds__(256) void embed_ln_kernel(
    const int* __restrict__ x, const float* __restrict__ wemb,
    const float* __restrict__ pemb, const float* __restrict__ temb,
    const float* __restrict__ lnw, const float* __restrict__ lnb,
    f16* __restrict__ out) {
  int row = blockIdx.x;
  int s = row & (SEQ - 1);
  int tok = x[row];
  const float* we = wemb + (size_t)tok * HID;
  const float* pe = pemb + (size_t)s * HID;
  int c = threadIdx.x;
  float e0 = we[c] + pe[c] + temb[c];
  float e1 = we[c + 256] + pe[c + 256] + temb[c + 256];
  float s1 = e0 + e1, s2 = e0 * e0 + e1 * e1;
  #pragma unroll
  for (int off = 32; off > 0; off >>= 1) {
    s1 += __shfl_down(s1, off, 64);
    s2 += __shfl_down(s2, off, 64);
  }
  __shared__ float r1[4], r2[4];
  int wid = threadIdx.x >> 6, lane = threadIdx.x & 63;
  if (lane == 0) { r1[wid] = s1; r2[wid] = s2; }
  __syncthreads();
  float S1 = r1[0] + r1[1] + r1[2] + r1[3];
  float S2 = r2[0] + r2[1] + r2[2] + r2[3];
  float m = S1 * (1.0f / HID);
  float v = S2 * (1.0f / HID) - m * m;
  float inv = rsqrtf(v + 1e-12f);
  f16* o = out + (size_t)row * HID;
  o[c]       = (f16)((e0 - m) * inv * lnw[c]       + lnb[c]);
  o[c + 256] = (f16)((e1 - m) * inv * lnw[c + 256] + lnb[c + 256]);
}

// ---------------------------------------------------------------------------
// f32 -> f16 cast (n % 4 == 0)
// ---------------------------------------------------------------------------
__global__ __launch_bounds__(256) void cast_f16_kernel(
    const float* __restrict__ in, f16* __restrict__ out, int n) {
  int i = (blockIdx.x * 256 + threadIdx.x) * 4;
  if (i < n) {
    float4 v = *(const float4*)(in + i);
    f16x4 o = {(f16)v.x, (f16)v.y, (f16)v.z, (f16)v.w};
    *(f16x4*)(out + i) = o;
  }
}

// ---------------------------------------------------------------------------
// per-head transpose+cast: Mt[h][t][s] = (f16) M[h][s][t]   (1024x1024 x 8)
// ---------------------------------------------------------------------------
__global__ __launch_bounds__(256) void mtrans_kernel(
    const float* __restrict__ M, f16* __restrict__ Mt) {
  __shared__ float T[32][33];
  int h = blockIdx.z;
  int s0 = blockIdx.y * 32, t0 = blockIdx.x * 32;
  int tx = threadIdx.x & 31, ty = threadIdx.x >> 5;   // ty 0..7
  const float* Mh = M + ((size_t)h << 20);
  #pragma unroll
  for (int i = 0; i < 32; i += 8)
    T[ty + i][tx] = Mh[((size_t)(s0 + ty + i) << 10) + t0 + tx];
  __syncthreads();
  f16* Mth = Mt + ((size_t)h << 20);
  #pragma unroll
  for (int i = 0; i < 32; i += 8)
    Mth[((size_t)(t0 + ty + i) << 10) + s0 + tx] = (f16)T[tx][ty + i];
}

// ---------------------------------------------------------------------------
extern "C" void kernel_launch(void* const* d_in, const int* in_sizes, int n_in,
                              void* d_out, int out_size, void* d_ws, size_t ws_size,
                              hipStream_t stream) {
  const int*   x        = (const int*)d_in[0];
  const float* wemb     = (const float*)d_in[1];
  const float* pemb     = (const float*)d_in[2];
  const float* temb     = (const float*)d_in[3];
  const float* lnw      = (const float*)d_in[4];
  const float* lnb      = (const float*)d_in[5];
  const float* init_d   = (const float*)d_in[6];
  const float* init_b   = (const float*)d_in[7];
  const float* init_M   = (const float*)d_in[8];
  const float* inter0_d = (const float*)d_in[9];
  const float* inter0_b = (const float*)d_in[10];
  const float* inter0_M = (const float*)d_in[11];
  const float* final_d  = (const float*)d_in[12];
  const float* final_b  = (const float*)d_in[13];
  float* out = (float*)d_out;

  // aliased f16 workspace regions (bytes):
  char* ws = (char*)d_ws;
  f16* R0 = (f16*)(ws);                 //  8.4MB: X0 (8192x512)  then W2f (2048x2048)
  f16* R1 = (f16*)(ws + 8388608);       //  2.1MB: W1f (2048x512) then W3f (512x2048)
  f16* R2 = (f16*)(ws + 10485760);      // 16.8MB: Mt1 then Mt2   (8x1024x1024)
  f16* R3 = (f16*)(ws + 27262976);      // 33.6MB: Xt1 then bufD  (8192x2048)
  f16* R4 = (f16*)(ws + 60817408);      // 33.6MB: bufB
  f16* R5 = (f16*)(ws + 94371840);      // 33.6MB: Xt2

  // 1. embeddings + LN -> X0 (f16)
  embed_ln_kernel<<<ROWS, 256, 0, stream>>>(x, wemb, pemb, temb, lnw, lnb, R0);
  // 2. W1 -> f16 ; Mt1
  cast_f16_kernel<<<(INTER * HID / 4 + 255) / 256, 256, 0, stream>>>(init_d, R1, INTER * HID);
  mtrans_kernel<<<dim3(32, 32, 8), 256, 0, stream>>>(init_M, R2);
  // 3. gemm1: Xt1 = X0 @ W1^T  (transposed-per-head epilogue)
  gemm_t_kernel<<<dim3(INTER / 128, ROWS / 128), 256, 0, stream>>>(R0, R1, R3, HID);
  // 4. mut1 -> bufB
  mut_kernel<<<dim3(DH / 128, SEQ / 128, BATCH * NHEAD), 256, 0, stream>>>(R2, R3, init_b, R4);
  // 5. W2 -> f16 (over X0) ; Mt2 (over Mt1)
  cast_f16_kernel<<<(INTER * INTER / 4 + 255) / 256, 256, 0, stream>>>(inter0_d, R0, INTER * INTER);
  mtrans_kernel<<<dim3(32, 32, 8), 256, 0, stream>>>(inter0_M, R2);
  // 6. gemm2: Xt2 = bufB @ W2^T
  gemm_t_kernel<<<dim3(INTER / 128, ROWS / 128), 256, 0, stream>>>(R4, R0, R5, INTER);
  // 7. mut2 -> bufD (over Xt1)
  mut_kernel<<<dim3(DH / 128, SEQ / 128, BATCH * NHEAD), 256, 0, stream>>>(R2, R5, inter0_b, R3);
  // 8. W3 -> f16 (over W1f)
  cast_f16_kernel<<<(HID * INTER / 4 + 255) / 256, 256, 0, stream>>>(final_d, R1, HID * INTER);
  // 9. gemm3: out = bufD @ W3^T + bias (fp32 out)
  gemm_out_kernel<<<dim3(HID / 128, ROWS / 128), 256, 0, stream>>>(R3, R1, final_b, out, INTER, HID);
}

// Round 4
// 454.747 us; speedup vs baseline: 4.7249x; 1.0549x over previous
//
#include <hip/hip_runtime.h>

typedef _Float16 f16;
typedef _Float16 f16x4 __attribute__((ext_vector_type(4)));
typedef _Float16 f16x8 __attribute__((ext_vector_type(8)));
typedef float    f32x4 __attribute__((ext_vector_type(4)));

#define SEQ   1024
#define HID   512
#define NHEAD 8
#define DH    256
#define INTER 2048
#define BATCH 8
#define ROWS  (BATCH * SEQ)   // 8192

// ---------------------------------------------------------------------------
// core: C(128x128) += A(128xK) * B^T(128xK), both operands k-fast row-major,
// ld == K. BK=32, sync reg->LDS staging, LDS double-buffer (1 barrier/slab),
// XOR-swizzled k-octet placement (breaks the 8-way ds_read_b128 bank
// conflict: row r, octet q stored at r*32 + (q ^ (((r>>1)&3)<<3))).
// 16x16x32 f16 MFMA, 4 waves x (4x4 tiles). C/D: col=lane&15, row=(lane>>4)*4+r.
// ---------------------------------------------------------------------------
__device__ __forceinline__ void mm_core(const f16* __restrict__ At,
                                        const f16* __restrict__ Bt,
                                        int K, f32x4 (&acc)[4][4]) {
  __shared__ __align__(16) f16 As[2 * 4096];
  __shared__ __align__(16) f16 Bs[2 * 4096];
  const int tid  = threadIdx.x;
  const int lane = tid & 63, wv = tid >> 6;
  const int wm = (wv >> 1) * 64, wn = (wv & 1) * 64;
  const int lrow  = lane & 15;
  const int kfrag = (lane >> 4) * 8;
  // staging: 512 chunks of 16B per 128x32 tile; chunk c -> row c>>2, k (c&3)*8
  const int c1 = wv * 64 + lane;      // 0..255  (chunk id, first 64 rows)
  const int r1 = c1 >> 2, kq1 = (c1 & 3) * 8;
  const int r2 = r1 + 64;             // second 64 rows
  const int e1 = r1 * 32 + (kq1 ^ (((r1 >> 1) & 3) << 3));
  const int e2 = r2 * 32 + (kq1 ^ (((r2 >> 1) & 3) << 3));
  const f16* Ap1 = At + (size_t)r1 * K + kq1;
  const f16* Ap2 = At + (size_t)r2 * K + kq1;
  const f16* Bp1 = Bt + (size_t)r1 * K + kq1;
  const f16* Bp2 = Bt + (size_t)r2 * K + kq1;
  int4 ra1 = *(const int4*)Ap1;
  int4 ra2 = *(const int4*)Ap2;
  int4 rb1 = *(const int4*)Bp1;
  int4 rb2 = *(const int4*)Bp2;
  // stage slab 0 into buffer 0
  *(int4*)&As[e1] = ra1;
  *(int4*)&As[e2] = ra2;
  *(int4*)&Bs[e1] = rb1;
  *(int4*)&Bs[e2] = rb2;
  if (K > 32) {      // prefetch slab 1
    ra1 = *(const int4*)(Ap1 + 32);
    ra2 = *(const int4*)(Ap2 + 32);
    rb1 = *(const int4*)(Bp1 + 32);
    rb2 = *(const int4*)(Bp2 + 32);
  }
  // swizzled frag offsets
  int aoff[4], boff[4];
  #pragma unroll
  for (int t = 0; t < 4; ++t) {
    int ra = wm + t * 16 + lrow;
    aoff[t] = ra * 32 + (kfrag ^ (((ra >> 1) & 3) << 3));
    int rb = wn + t * 16 + lrow;
    boff[t] = rb * 32 + (kfrag ^ (((rb >> 1) & 3) << 3));
  }
  __syncthreads();
  int cur = 0;
  for (int k0 = 0; k0 < K; k0 += 32) {
    const int nxt = (cur ^ 1) * 4096;
    if (k0 + 32 < K) {
      // stage slab k0+32 (held in regs since last iter) into other buffer;
      // safe: previous readers of that buffer drained at last barrier.
      *(int4*)&As[nxt + e1] = ra1;
      *(int4*)&As[nxt + e2] = ra2;
      *(int4*)&Bs[nxt + e1] = rb1;
      *(int4*)&Bs[nxt + e2] = rb2;
      if (k0 + 64 < K) {  // prefetch slab k0+64; latency hides under MFMA
        ra1 = *(const int4*)(Ap1 + k0 + 64);
        ra2 = *(const int4*)(Ap2 + k0 + 64);
        rb1 = *(const int4*)(Bp1 + k0 + 64);
        rb2 = *(const int4*)(Bp2 + k0 + 64);
      }
    }
    const int cb = cur * 4096;
    f16x8 af[4], bf[4];
    #pragma unroll
    for (int t = 0; t < 4; ++t) {
      af[t] = *(const f16x8*)&As[cb + aoff[t]];
      bf[t] = *(const f16x8*)&Bs[cb + boff[t]];
    }
    #pragma unroll
    for (int i = 0; i < 4; ++i)
      #pragma unroll
      for (int j = 0; j < 4; ++j)
        acc[i][j] = __builtin_amdgcn_mfma_f32_16x16x32_f16(af[i], bf[j],
                                                           acc[i][j], 0, 0, 0);
    __syncthreads();
    cur ^= 1;
  }
}

__device__ __forceinline__ void zero_acc(f32x4 (&acc)[4][4]) {
  f32x4 z = {0.f, 0.f, 0.f, 0.f};
  #pragma unroll
  for (int i = 0; i < 4; ++i)
    #pragma unroll
    for (int j = 0; j < 4; ++j) acc[i][j] = z;
}

// ---------------------------------------------------------------------------
// GEMM writing activation in per-head transposed layout Xt[b,h,d,s] (f16).
// A: [8192][K] f16, W: [2048][K] f16. N fixed = 2048 (8 heads x 256).
// ---------------------------------------------------------------------------
__global__ __launch_bounds__(256) void gemm_t_kernel(
    const f16* __restrict__ A, const f16* __restrict__ W,
    f16* __restrict__ Xt, int K) {
  int row0 = blockIdx.y * 128, col0 = blockIdx.x * 128;
  f32x4 acc[4][4];
  zero_acc(acc);
  mm_core(A + (size_t)row0 * K, W + (size_t)col0 * K, K, acc);
  int tid = threadIdx.x, lane = tid & 63, wv = tid >> 6;
  int wm = (wv >> 1) * 64, wn = (wv & 1) * 64;
  int cn = lane & 15, rbase = (lane >> 4) * 4;
  int b = row0 >> 10, sbase = row0 & 1023;
  #pragma unroll
  for (int mt = 0; mt < 4; ++mt) {
    int s = sbase + wm + mt * 16 + rbase;            // 4 consecutive s
    #pragma unroll
    for (int nt = 0; nt < 4; ++nt) {
      int n = col0 + wn + nt * 16 + cn;
      int h = n >> 8, d = n & 255;
      f16x4 v = {(f16)acc[mt][nt][0], (f16)acc[mt][nt][1],
                 (f16)acc[mt][nt][2], (f16)acc[mt][nt][3]};
      *(f16x4*)&Xt[(((size_t)(b * 8 + h) * 256 + d) << 10) + s] = v;
    }
  }
}

// ---------------------------------------------------------------------------
// per-head seq mix + bias + square:
// Y[(b,t),(h,d)] = ( sum_s Mt[h,t,s] * Xt[b,h,d,s] + bias[h,d] )^2   (f16 out)
// ---------------------------------------------------------------------------
__global__ __launch_bounds__(256) void mut_kernel(
    const f16* __restrict__ Mt, const f16* __restrict__ Xt,
    const float* __restrict__ bias, f16* __restrict__ Y) {
  int b = blockIdx.z >> 3, h = blockIdx.z & 7;
  int t0 = blockIdx.y * 128, d0 = blockIdx.x * 128;
  f32x4 acc[4][4];
  zero_acc(acc);
  const f16* Ap = Mt + ((size_t)h << 20) + ((size_t)t0 << 10);
  const f16* Bp = Xt + (((size_t)(b * 8 + h) * 256 + d0) << 10);
  mm_core(Ap, Bp, SEQ, acc);
  int tid = threadIdx.x, lane = tid & 63, wv = tid >> 6;
  int wm = (wv >> 1) * 64, wn = (wv & 1) * 64;
  int cn = lane & 15, rbase = (lane >> 4) * 4;
  #pragma unroll
  for (int mt = 0; mt < 4; ++mt) {
    int t = t0 + wm + mt * 16 + rbase;
    #pragma unroll
    for (int nt = 0; nt < 4; ++nt) {
      int d = d0 + wn + nt * 16 + cn;
      float bb = bias[(h << 8) + d];
      size_t base = (((size_t)(b << 10) + t) << 11) + (h << 8) + d;
      #pragma unroll
      for (int r = 0; r < 4; ++r) {
        float v = acc[mt][nt][r] + bb;
        Y[base + (size_t)r * INTER] = (f16)(v * v);
      }
    }
  }
}

// ---------------------------------------------------------------------------
// final GEMM: out fp32 = A @ W^T + bias.  A: [8192][K] f16, W: [N][K] f16.
// ---------------------------------------------------------------------------
__global__ __launch_bounds__(256) void gemm_out_kernel(
    const f16* __restrict__ A, const f16* __restrict__ W,
    const float* __restrict__ bias, float* __restrict__ out, int K, int N) {
  int row0 = blockIdx.y * 128, col0 = blockIdx.x * 128;
  f32x4 acc[4][4];
  zero_acc(acc);
  mm_core(A + (size_t)row0 * K, W + (size_t)col0 * K, K, acc);
  int tid = threadIdx.x, lane = tid & 63, wv = tid >> 6;
  int wm = (wv >> 1) * 64, wn = (wv & 1) * 64;
  int cn = lane & 15, rbase = (lane >> 4) * 4;
  #pragma unroll
  for (int mt = 0; mt < 4; ++mt) {
    int r0 = row0 + wm + mt * 16 + rbase;
    #pragma unroll
    for (int nt = 0; nt < 4; ++nt) {
      int col = col0 + wn + nt * 16 + cn;
      float bb = bias[col];
      #pragma unroll
      for (int r = 0; r < 4; ++r)
        out[(size_t)(r0 + r) * N + col] = acc[mt][nt][r] + bb;
    }
  }
}

// ---------------------------------------------------------------------------
// embeddings + layernorm -> f16
// ---------------------------------------------------------------------------
__global__ __launch_bounds__(256) void embed_ln_kernel(
    const int* __restrict__ x, const float* __restrict__ wemb,
    const float* __restrict__ pemb, const float* __restrict__ temb,
    const float* __restrict__ lnw, const float* __restrict__ lnb,
    f16* __restrict__ out) {
  int row = blockIdx.x;
  int s = row & (SEQ - 1);
  int tok = x[row];
  const float* we = wemb + (size_t)tok * HID;
  const float* pe = pemb + (size_t)s * HID;
  int c = threadIdx.x;
  float e0 = we[c] + pe[c] + temb[c];
  float e1 = we[c + 256] + pe[c + 256] + temb[c + 256];
  float s1 = e0 + e1, s2 = e0 * e0 + e1 * e1;
  #pragma unroll
  for (int off = 32; off > 0; off >>= 1) {
    s1 += __shfl_down(s1, off, 64);
    s2 += __shfl_down(s2, off, 64);
  }
  __shared__ float r1[4], r2[4];
  int wid = threadIdx.x >> 6, lane = threadIdx.x & 63;
  if (lane == 0) { r1[wid] = s1; r2[wid] = s2; }
  __syncthreads();
  float S1 = r1[0] + r1[1] + r1[2] + r1[3];
  float S2 = r2[0] + r2[1] + r2[2] + r2[3];
  float m = S1 * (1.0f / HID);
  float v = S2 * (1.0f / HID) - m * m;
  float inv = rsqrtf(v + 1e-12f);
  f16* o = out + (size_t)row * HID;
  o[c]       = (f16)((e0 - m) * inv * lnw[c]       + lnb[c]);
  o[c + 256] = (f16)((e1 - m) * inv * lnw[c + 256] + lnb[c + 256]);
}

// ---------------------------------------------------------------------------
// f32 -> f16 cast (n % 4 == 0)
// ---------------------------------------------------------------------------
__global__ __launch_bounds__(256) void cast_f16_kernel(
    const float* __restrict__ in, f16* __restrict__ out, int n) {
  int i = (blockIdx.x * 256 + threadIdx.x) * 4;
  if (i < n) {
    float4 v = *(const float4*)(in + i);
    f16x4 o = {(f16)v.x, (f16)v.y, (f16)v.z, (f16)v.w};
    *(f16x4*)(out + i) = o;
  }
}

// ---------------------------------------------------------------------------
// per-head transpose+cast: Mt[h][t][s] = (f16) M[h][s][t]   (1024x1024 x 8)
// ---------------------------------------------------------------------------
__global__ __launch_bounds__(256) void mtrans_kernel(
    const float* __restrict__ M, f16* __restrict__ Mt) {
  __shared__ float T[32][33];
  int h = blockIdx.z;
  int s0 = blockIdx.y * 32, t0 = blockIdx.x * 32;
  int tx = threadIdx.x & 31, ty = threadIdx.x >> 5;   // ty 0..7
  const float* Mh = M + ((size_t)h << 20);
  #pragma unroll
  for (int i = 0; i < 32; i += 8)
    T[ty + i][tx] = Mh[((size_t)(s0 + ty + i) << 10) + t0 + tx];
  __syncthreads();
  f16* Mth = Mt + ((size_t)h << 20);
  #pragma unroll
  for (int i = 0; i < 32; i += 8)
    Mth[((size_t)(t0 + ty + i) << 10) + s0 + tx] = (f16)T[tx][ty + i];
}

// ---------------------------------------------------------------------------
extern "C" void kernel_launch(void* const* d_in, const int* in_sizes, int n_in,
                              void* d_out, int out_size, void* d_ws, size_t ws_size,
                              hipStream_t stream) {
  const int*   x        = (const int*)d_in[0];
  const float* wemb     = (const float*)d_in[1];
  const float* pemb     = (const float*)d_in[2];
  const float* temb     = (const float*)d_in[3];
  const float* lnw      = (const float*)d_in[4];
  const float* lnb      = (const float*)d_in[5];
  const float* init_d   = (const float*)d_in[6];
  const float* init_b   = (const float*)d_in[7];
  const float* init_M   = (const float*)d_in[8];
  const float* inter0_d = (const float*)d_in[9];
  const float* inter0_b = (const float*)d_in[10];
  const float* inter0_M = (const float*)d_in[11];
  const float* final_d  = (const float*)d_in[12];
  const float* final_b  = (const float*)d_in[13];
  float* out = (float*)d_out;

  // aliased f16 workspace regions (bytes):
  char* ws = (char*)d_ws;
  f16* R0 = (f16*)(ws);                 //  8.4MB: X0 (8192x512)  then W2f (2048x2048)
  f16* R1 = (f16*)(ws + 8388608);       //  2.1MB: W1f (2048x512) then W3f (512x2048)
  f16* R2 = (f16*)(ws + 10485760);      // 16.8MB: Mt1 then Mt2   (8x1024x1024)
  f16* R3 = (f16*)(ws + 27262976);      // 33.6MB: Xt1 then bufD  (8192x2048)
  f16* R4 = (f16*)(ws + 60817408);      // 33.6MB: bufB
  f16* R5 = (f16*)(ws + 94371840);      // 33.6MB: Xt2

  // 1. embeddings + LN -> X0 (f16)
  embed_ln_kernel<<<ROWS, 256, 0, stream>>>(x, wemb, pemb, temb, lnw, lnb, R0);
  // 2. W1 -> f16 ; Mt1
  cast_f16_kernel<<<(INTER * HID / 4 + 255) / 256, 256, 0, stream>>>(init_d, R1, INTER * HID);
  mtrans_kernel<<<dim3(32, 32, 8), 256, 0, stream>>>(init_M, R2);
  // 3. gemm1: Xt1 = X0 @ W1^T  (transposed-per-head epilogue)
  gemm_t_kernel<<<dim3(INTER / 128, ROWS / 128), 256, 0, stream>>>(R0, R1, R3, HID);
  // 4. mut1 -> bufB
  mut_kernel<<<dim3(DH / 128, SEQ / 128, BATCH * NHEAD), 256, 0, stream>>>(R2, R3, init_b, R4);
  // 5. W2 -> f16 (over X0) ; Mt2 (over Mt1)
  cast_f16_kernel<<<(INTER * INTER / 4 + 255) / 256, 256, 0, stream>>>(inter0_d, R0, INTER * INTER);
  mtrans_kernel<<<dim3(32, 32, 8), 256, 0, stream>>>(inter0_M, R2);
  // 6. gemm2: Xt2 = bufB @ W2^T
  gemm_t_kernel<<<dim3(INTER / 128, ROWS / 128), 256, 0, stream>>>(R4, R0, R5, INTER);
  // 7. mut2 -> bufD (over Xt1)
  mut_kernel<<<dim3(DH / 128, SEQ / 128, BATCH * NHEAD), 256, 0, stream>>>(R2, R5, inter0_b, R3);
  // 8. W3 -> f16 (over W1f)
  cast_f16_kernel<<<(HID * INTER / 4 + 255) / 256, 256, 0, stream>>>(final_d, R1, HID * INTER);
  // 9. gemm3: out = bufD @ W3^T + bias (fp32 out)
  gemm_out_kernel<<<dim3(HID / 128, ROWS / 128), 256, 0, stream>>>(R3, R1, final_b, out, INTER, HID);
}